// Round 13
// baseline (62.419 us; speedup 1.0000x reference)
//
#include <hip/hip_runtime.h>

// Problem: B=16, T=4096, D=512, R=256. Output (B,T,R+1) float32.
// build_kt: normalized bf16 K panel, fragment-blocked [b][ks][rt] 1KB tiles.
//   kb[b*262144 + (ks*16 + rt)*1024 + (c*4+g)*16] = K[rt*16+c][ks*32+g*8 ..+8)
// nystrom_mfma: TM=32 tile, 512 thr / 8 waves; wave w owns all 32 t x
// r in [32w,32w+32): acc[2][2]. Small footprint -> 6 waves/SIMD, 3 blocks/CU
// (24 waves/CU) for latency hiding. Named-register rings, literal indices.

typedef float f32x4 __attribute__((ext_vector_type(4)));
typedef short s16x8 __attribute__((ext_vector_type(8)));
typedef unsigned short u16x4 __attribute__((ext_vector_type(4)));
typedef unsigned short u16x8 __attribute__((ext_vector_type(8)));

__device__ __forceinline__ unsigned short f2bf(float f) {
    unsigned u = __builtin_bit_cast(unsigned, f);
    return (unsigned short)((u + 0x7FFFu + ((u >> 16) & 1u)) >> 16);
}

__device__ __forceinline__ int load_lm(const void* lms_raw, int idx) {
    const int* l32 = (const int*)lms_raw;
    if (l32[1] == 0) {
        const long long* l64 = (const long long*)lms_raw;
        return (int)l64[idx];
    }
    return l32[idx];
}

__device__ __forceinline__ void scalars(const float* gw, const float* ta,
                                        float& a0, float& a1, float& a2, float& atd) {
    float w0 = gw[0], w1 = gw[1], w2 = gw[2];
    float wm = fmaxf(w0, fmaxf(w1, w2));
    float e0 = __expf(w0 - wm), e1 = __expf(w1 - wm), e2 = __expf(w2 - wm);
    float einv = 1.0f / (e0 + e1 + e2);
    a0 = e0 * einv; a1 = e1 * einv; a2 = e2 * einv;
    float tv = ta[0];
    atd = (tv > 0.0f) ? (tv + log1pf(__expf(-tv))) : log1pf(__expf(tv));
}

// ---------------------------------------------------------------------------
// Kernel 1: normalized K panel, fragment-blocked. One wave per (b, r).
// ---------------------------------------------------------------------------
__global__ void build_kt(const float* __restrict__ z,
                         const void* __restrict__ lms_raw,
                         unsigned char* __restrict__ kb) {
    const int b = blockIdx.x >> 8;
    const int r = blockIdx.x & 255;
    const int L = threadIdx.x;
    const int lm = load_lm(lms_raw, r);

    const f32x4* zrow = (const f32x4*)(z + ((size_t)b * 4096 + (size_t)lm) * 512);
    f32x4 v0 = zrow[L * 2 + 0];
    f32x4 v1 = zrow[L * 2 + 1];
    float ss = v0.x*v0.x + v0.y*v0.y + v0.z*v0.z + v0.w*v0.w
             + v1.x*v1.x + v1.y*v1.y + v1.z*v1.z + v1.w*v1.w;
    #pragma unroll
    for (int off = 32; off >= 1; off >>= 1) ss += __shfl_xor(ss, off, 64);
    float inv = 1.0f / fmaxf(sqrtf(ss), 1e-12f);

    u16x8 o;
    o[0]=f2bf(v0.x*inv); o[1]=f2bf(v0.y*inv); o[2]=f2bf(v0.z*inv); o[3]=f2bf(v0.w*inv);
    o[4]=f2bf(v1.x*inv); o[5]=f2bf(v1.y*inv); o[6]=f2bf(v1.z*inv); o[7]=f2bf(v1.w*inv);

    const int rt = r >> 4;
    const int c  = r & 15;
    const int ks = L >> 2;
    const int g  = L & 3;
    size_t off = (size_t)b * 262144
               + (size_t)(ks * 16 + rt) * 1024 + (size_t)(c * 4 + g) * 16;
    *(u16x8*)(kb + off) = o;
}

// --- macro-expanded K-loop pieces (all indices literal) ---------------------
#define LDB(S, KS) do { \
    B##S##0 = *(const u16x8*)(kbw + (size_t)((KS) * 16 + rt0 + 0) * 1024); \
    B##S##1 = *(const u16x8*)(kbw + (size_t)((KS) * 16 + rt0 + 1) * 1024); \
} while (0)

#define LDA(AV, KK) do { \
    int kw_ = ((KK) * 64 + g * 16) ^ swz; \
    AV##0 = *(const s16x8*)(qtile + (c     ) * 1024 + kw_); \
    AV##1 = *(const s16x8*)(qtile + (c + 16) * 1024 + kw_); \
} while (0)

#define MM(AV, S) do { \
    s16x8 ba_ = __builtin_bit_cast(s16x8, B##S##0); \
    s16x8 bb_ = __builtin_bit_cast(s16x8, B##S##1); \
    acc00 = __builtin_amdgcn_mfma_f32_16x16x32_bf16(AV##0, ba_, acc00, 0, 0, 0); \
    acc01 = __builtin_amdgcn_mfma_f32_16x16x32_bf16(AV##0, bb_, acc01, 0, 0, 0); \
    acc10 = __builtin_amdgcn_mfma_f32_16x16x32_bf16(AV##1, ba_, acc10, 0, 0, 0); \
    acc11 = __builtin_amdgcn_mfma_f32_16x16x32_bf16(AV##1, bb_, acc11, 0, 0, 0); \
} while (0)

// step: prefetch next A (LDS), 4 MFMAs, reload this B slot (distance 2)
#define STEP(KS, AC, AN, S) do { \
    if ((KS) + 1 < 16) LDA(AN, (KS) + 1); \
    MM(AC, S); \
    if ((KS) + 2 < 16) LDB(S, (KS) + 2); \
} while (0)

// ---------------------------------------------------------------------------
// Kernel 2: MFMA main. Block = (b, 32 t-rows) x 256 r; 8 waves (512 thr).
// ---------------------------------------------------------------------------
__global__ __launch_bounds__(512, 6) void nystrom_mfma(const float* __restrict__ z,
                                                       const float* __restrict__ gw,
                                                       const float* __restrict__ ta,
                                                       const void* __restrict__ lms_raw,
                                                       const unsigned char* __restrict__ kb,
                                                       float* __restrict__ out) {
    __shared__ unsigned char qtile[32 * 512 * 2];  // 32 KB swizzled bf16 Q tile
    __shared__ float s_invn[32];
    __shared__ float s_rs[8][32];
    __shared__ float s_rsi[32];

    const int tid  = threadIdx.x;
    const int lane = tid & 63;
    const int w    = tid >> 6;                 // wave 0..7

    // XCD-aware swizzle (2048 blocks, 8 XCDs): 2 batches per XCD.
    const int wgid = (blockIdx.x & 7) * 256 + (blockIdx.x >> 3);
    const int b    = wgid >> 7;                // 128 t-tiles per batch
    const int t0   = (wgid & 127) * 32;

    const int c = lane & 15;
    const int g = lane >> 4;

    float sa0, sa1, sa2, alpha_td;
    scalars(gw, ta, sa0, sa1, sa2, alpha_td);
    const float C0 = 0.5f * (sa0 - sa1);

    const unsigned char* kbw = kb + (size_t)b * 262144 + (size_t)(c * 4 + g) * 16;
    const int rt0 = 2 * w;

    // B ring: 2 named slots x 2 frags; issue ks=0,1 before staging.
    u16x8 B00, B01, B10, B11;
    LDB(0, 0); LDB(1, 1);

    // landmark data (independent of staging) hoisted ahead of K-loop
    const int lmv0 = load_lm(lms_raw, 32 * w + c);
    const int lmv1 = load_lm(lms_raw, 32 * w + 16 + c);
    const float elm0 = __expf(alpha_td * (float)lmv0 * (1.0f / 4096.0f));
    const float elm1 = __expf(alpha_td * (float)lmv1 * (1.0f / 4096.0f));

    // --- stage z -> bf16 LDS (XOR swizzle) + row norms; ONE batch of 8 ---
    {
        const int row = tid >> 4, part = tid & 15;  // 32 rows x 16 parts
        const f32x4* zr = (const f32x4*)(z + ((size_t)b * 4096 + (size_t)(t0 + row)) * 512);
        f32x4 v[8];
        #pragma unroll
        for (int i = 0; i < 8; ++i) v[i] = zr[part + 16 * i];
        float ss = 0.0f;
        #pragma unroll
        for (int i = 0; i < 8; ++i) {
            f32x4 vv = v[i];
            ss += vv.x*vv.x + vv.y*vv.y + vv.z*vv.z + vv.w*vv.w;
            u16x4 hh; hh[0]=f2bf(vv.x); hh[1]=f2bf(vv.y); hh[2]=f2bf(vv.z); hh[3]=f2bf(vv.w);
            int within = ((part + 16 * i) * 8) ^ ((row & 7) << 4);
            *(u16x4*)(qtile + row * 1024 + within) = hh;
        }
        ss += __shfl_xor(ss, 1, 64);
        ss += __shfl_xor(ss, 2, 64);
        ss += __shfl_xor(ss, 4, 64);
        ss += __shfl_xor(ss, 8, 64);
        if (part == 0) s_invn[row] = 1.0f / fmaxf(sqrtf(ss), 1e-12f);
    }
    __syncthreads();

    f32x4 acc00 = {0,0,0,0}, acc01 = {0,0,0,0};
    f32x4 acc10 = {0,0,0,0}, acc11 = {0,0,0,0};

    const int swz = (c & 7) << 4;
    s16x8 A00, A01, A10, A11;
    LDA(A0, 0);

    STEP( 0, A0, A1, 0);  STEP( 1, A1, A0, 1);
    STEP( 2, A0, A1, 0);  STEP( 3, A1, A0, 1);
    STEP( 4, A0, A1, 0);  STEP( 5, A1, A0, 1);
    STEP( 6, A0, A1, 0);  STEP( 7, A1, A0, 1);
    STEP( 8, A0, A1, 0);  STEP( 9, A1, A0, 1);
    STEP(10, A0, A1, 0);  STEP(11, A1, A0, 1);
    STEP(12, A0, A1, 0);  STEP(13, A1, A0, 1);
    STEP(14, A0, A1, 0);  STEP(15, A1, A0, 1);

    // gather named regs into literal-indexed arrays for the epilogue
    f32x4 acc[2][2] = {{acc00, acc01}, {acc10, acc11}};
    const int   lmv[2] = {lmv0, lmv1};
    const float elm[2] = {elm0, elm1};

    // --- epilogue ---
    float eA[2], eB[4];
    #pragma unroll
    for (int tf = 0; tf < 2; ++tf)
        eA[tf] = __expf(-alpha_td * (float)(t0 + tf * 16) * (1.0f / 4096.0f));
    #pragma unroll
    for (int q = 0; q < 4; ++q)
        eB[q] = __expf(-alpha_td * (float)(g * 4 + q) * (1.0f / 4096.0f));
    float invn[2][4];
    #pragma unroll
    for (int tf = 0; tf < 2; ++tf)
        #pragma unroll
        for (int q = 0; q < 4; ++q)
            invn[tf][q] = s_invn[tf * 16 + g * 4 + q];

    float phi[2][2][4];
    float rsum[2][4];
    #pragma unroll
    for (int tf = 0; tf < 2; ++tf) {
        #pragma unroll
        for (int q = 0; q < 4; ++q) {
            int tg = t0 + tf * 16 + g * 4 + q;
            float et = eA[tf] * eB[q];
            float s = 0.0f;
            #pragma unroll
            for (int nf = 0; nf < 2; ++nf) {
                float v = acc[tf][nf][q] * invn[tf][q];
                float p;
                if (lmv[nf] < tg) {
                    float c2 = v * v;
                    float p1 = fmaf(0.5f, v, 0.5f);
                    float p2 = fmaf(1.5f, c2, -0.5f);
                    float p3 = v * fmaf(2.5f, c2, -1.5f);
                    p = (sa0 * p1 + sa1 * p2 + sa2 * p3) * (et * elm[nf]);
                } else {
                    p = C0;
                }
                phi[tf][nf][q] = p;
                s += p;
            }
            rsum[tf][q] = s;
        }
    }

    #pragma unroll
    for (int tf = 0; tf < 2; ++tf)
        #pragma unroll
        for (int q = 0; q < 4; ++q) {
            float s = rsum[tf][q];
            s += __shfl_xor(s, 1, 64);
            s += __shfl_xor(s, 2, 64);
            s += __shfl_xor(s, 4, 64);
            s += __shfl_xor(s, 8, 64);
            rsum[tf][q] = s;
        }
    if (c == 0) {
        #pragma unroll
        for (int tf = 0; tf < 2; ++tf)
            #pragma unroll
            for (int q = 0; q < 4; ++q)
                s_rs[w][tf * 16 + g * 4 + q] = rsum[tf][q];
    }
    __syncthreads();
    if (tid < 32) {
        float s = 0.0f;
        #pragma unroll
        for (int i = 0; i < 8; ++i) s += s_rs[i][tid];
        s_rsi[tid] = 1.0f / fmaxf(s, 1e-6f);
    }
    __syncthreads();

    #pragma unroll
    for (int tf = 0; tf < 2; ++tf)
        #pragma unroll
        for (int q = 0; q < 4; ++q) {
            int tl = tf * 16 + g * 4 + q;
            float ri = s_rsi[tl];
            size_t obase = ((size_t)b * 4096 + (size_t)(t0 + tl)) * 257
                         + (size_t)(32 * w + c);
            #pragma unroll
            for (int nf = 0; nf < 2; ++nf)
                out[obase + nf * 16] = phi[tf][nf][q] * ri;
        }
    if (tid < 32)
        out[((size_t)b * 4096 + (size_t)(t0 + tid)) * 257 + 256] = 1.0f;
}

// ---------------------------------------------------------------------------
extern "C" void kernel_launch(void* const* d_in, const int* in_sizes, int n_in,
                              void* d_out, int out_size, void* d_ws, size_t ws_size,
                              hipStream_t stream) {
    const float* z   = (const float*)d_in[0];
    const float* gw  = (const float*)d_in[1];
    const float* ta  = (const float*)d_in[2];
    const void*  lms = (const void*)d_in[3];
    float* out = (float*)d_out;
    unsigned char* kb = (unsigned char*)d_ws;   // 4 MB fragment-blocked panel

    build_kt<<<16 * 256, 64, 0, stream>>>(z, lms, kb);
    nystrom_mfma<<<2048, 512, 0, stream>>>(z, gw, ta, lms, kb, out);
}